// Round 1
// baseline (964.923 us; speedup 1.0000x reference)
//
#include <hip/hip_runtime.h>
#include <math.h>

#define E_    3
#define QE_   60000
#define QTOT  180000      // E_*QE_
#define P_    40
#define H_    20
#define NIMG_ 1800
#define NNZ_  14400000
#define BLK   256
#define NB    704         // ceil(QTOT/BLK)

// ---------------- zero init (d_out is poisoned 0xAA every launch) -----------
__global__ void zero_kernel(float* __restrict__ out, int n) {
    int i = blockIdx.x * blockDim.x + threadIdx.x;
    if (i < n) out[i] = 0.0f;
}

// ---------------- stable counting sort: per-block histograms ---------------
// g_hist layout: bucket-major g_hist[v*NB + b]
__global__ void hist_kernel(const int* __restrict__ img, int* __restrict__ g_hist) {
    __shared__ int h[NIMG_];
    const int t = threadIdx.x, b = blockIdx.x;
    for (int v = t; v < NIMG_; v += BLK) h[v] = 0;
    __syncthreads();
    int a = b * BLK + t;
    if (a < QTOT) atomicAdd(&h[img[a]], 1);
    __syncthreads();
    for (int v = t; v < NIMG_; v += BLK) g_hist[v * NB + b] = h[v];
}

// exclusive scan across blocks, per bucket; writes bucket totals
__global__ void scan_blocks_kernel(int* __restrict__ g_hist, int* __restrict__ g_total) {
    __shared__ int s[BLK];
    const int v = blockIdx.x, t = threadIdx.x;
    int carry = 0;
    for (int c = 0; c < NB; c += BLK) {
        int idx = c + t;
        int val = (idx < NB) ? g_hist[v * NB + idx] : 0;
        s[t] = val; __syncthreads();
        for (int off = 1; off < BLK; off <<= 1) {
            int tmp = (t >= off) ? s[t - off] : 0;
            __syncthreads();
            s[t] += tmp;
            __syncthreads();
        }
        int excl = s[t] - val;
        int tot  = s[BLK - 1];
        if (idx < NB) g_hist[v * NB + idx] = carry + excl;
        carry += tot;
        __syncthreads();
    }
    if (t == 0) g_total[v] = carry;
}

// exclusive scan over the 1800 bucket totals -> bucket base offsets
__global__ void scan_buckets_kernel(const int* __restrict__ g_total, int* __restrict__ g_base) {
    __shared__ int s[BLK];
    const int t = threadIdx.x;
    int carry = 0;
    for (int c = 0; c < NIMG_; c += BLK) {
        int idx = c + t;
        int val = (idx < NIMG_) ? g_total[idx] : 0;
        s[t] = val; __syncthreads();
        for (int off = 1; off < BLK; off <<= 1) {
            int tmp = (t >= off) ? s[t - off] : 0;
            __syncthreads();
            s[t] += tmp;
            __syncthreads();
        }
        if (idx < NIMG_) g_base[idx] = carry + (s[t] - val);
        carry += s[BLK - 1];
        __syncthreads();
    }
}

// stable rank per atom: base[img] + prefix-of-blocks + local stable rank
__global__ void rank_kernel(const int* __restrict__ img, const int* __restrict__ g_hist,
                            const int* __restrict__ g_base, int* __restrict__ rank) {
    __shared__ int simg[BLK];
    const int t = threadIdx.x, b = blockIdx.x;
    int a = b * BLK + t;
    int v = (a < QTOT) ? img[a] : -1;
    simg[t] = v;
    __syncthreads();
    if (a < QTOT) {
        int local = 0;
        for (int j = 0; j < BLK; ++j) {       // j uniform -> LDS broadcast
            if (j < t && simg[j] == v) local++;
        }
        rank[a] = g_base[v] + g_hist[v * NB + b] + local;
    }
}

// ---------------- per-atom MLP forward + backward ---------------------------
__global__ __launch_bounds__(BLK) void mlp_kernel(
    const float* __restrict__ fps, const float* __restrict__ W1, const float* __restrict__ b1,
    const float* __restrict__ W2, const float* __restrict__ b2, const float* __restrict__ W3,
    const float* __restrict__ b3, const int* __restrict__ img, const int* __restrict__ rank,
    float* __restrict__ energy, float* __restrict__ dEflat)
{
    __shared__ float sW1[P_ * H_], sW2[H_ * H_], sW3[H_], sB1[H_], sB2[H_];
    __shared__ float sB3;
    const int e = blockIdx.y;
    const int t = threadIdx.x;
    for (int i = t; i < P_ * H_; i += BLK) sW1[i] = W1[e * P_ * H_ + i];
    for (int i = t; i < H_ * H_; i += BLK) sW2[i] = W2[e * H_ * H_ + i];
    if (t < H_) { sW3[t] = W3[e * H_ + t]; sB1[t] = b1[e * H_ + t]; sB2[t] = b2[e * H_ + t]; }
    if (t == 0) sB3 = b3[e];
    __syncthreads();

    int q = blockIdx.x * BLK + t;
    if (q >= QE_) return;
    int a = e * QE_ + q;

    const float* xp = fps + (size_t)a * P_;
    float x[P_];
    #pragma unroll
    for (int p = 0; p < P_; p += 4) {
        float4 v4 = *(const float4*)(xp + p);
        x[p] = v4.x; x[p+1] = v4.y; x[p+2] = v4.z; x[p+3] = v4.w;
    }

    float h1v[H_], h2v[H_];
    #pragma unroll
    for (int i = 0; i < H_; ++i) {
        float z = sB1[i];
        #pragma unroll
        for (int p = 0; p < P_; ++p) z += x[p] * sW1[p * H_ + i];
        h1v[i] = tanhf(z);
    }
    #pragma unroll
    for (int i = 0; i < H_; ++i) {
        float z = sB2[i];
        #pragma unroll
        for (int j = 0; j < H_; ++j) z += h1v[j] * sW2[j * H_ + i];
        h2v[i] = tanhf(z);
    }
    float ea = sB3;
    #pragma unroll
    for (int i = 0; i < H_; ++i) ea += h2v[i] * sW3[i];
    atomicAdd(&energy[img[a]], ea);

    // backward
    float dz2[H_];
    #pragma unroll
    for (int i = 0; i < H_; ++i) dz2[i] = sW3[i] * (1.0f - h2v[i] * h2v[i]);
    float dz1[H_];
    #pragma unroll
    for (int i = 0; i < H_; ++i) {
        float d = 0.0f;
        #pragma unroll
        for (int j = 0; j < H_; ++j) d += sW2[i * H_ + j] * dz2[j];
        dz1[i] = d * (1.0f - h1v[i] * h1v[i]);
    }
    float* op = dEflat + (size_t)rank[a] * P_;
    #pragma unroll
    for (int p = 0; p < P_; p += 4) {
        float4 v4;
        float d0 = 0.f, d1 = 0.f, d2 = 0.f, d3 = 0.f;
        #pragma unroll
        for (int i = 0; i < H_; ++i) {
            d0 += sW1[(p    ) * H_ + i] * dz1[i];
            d1 += sW1[(p + 1) * H_ + i] * dz1[i];
            d2 += sW1[(p + 2) * H_ + i] * dz1[i];
            d3 += sW1[(p + 3) * H_ + i] * dz1[i];
        }
        v4.x = d0; v4.y = d1; v4.z = d2; v4.w = d3;
        *(float4*)(op + p) = v4;
    }
}

// ---------------- sparse COO scatter: force = -fprimes^T @ dE ---------------
__global__ void force_kernel(const int* __restrict__ rows, const int* __restrict__ cols,
                             const float* __restrict__ vals, const float* __restrict__ dEflat,
                             float* __restrict__ force) {
    int k = blockIdx.x * blockDim.x + threadIdx.x;
    if (k < NNZ_) {
        float contrib = -vals[k] * dEflat[rows[k]];
        atomicAdd(&force[cols[k]], contrib);
    }
}

extern "C" void kernel_launch(void* const* d_in, const int* in_sizes, int n_in,
                              void* d_out, int out_size, void* d_ws, size_t ws_size,
                              hipStream_t stream) {
    (void)in_sizes; (void)n_in; (void)out_size; (void)ws_size;
    const float* fps  = (const float*)d_in[0];
    const float* W1   = (const float*)d_in[1];
    const float* b1   = (const float*)d_in[2];
    const float* W2   = (const float*)d_in[3];
    const float* b2   = (const float*)d_in[4];
    const float* W3   = (const float*)d_in[5];
    const float* b3   = (const float*)d_in[6];
    const int*   img  = (const int*)d_in[7];
    const int*   rows = (const int*)d_in[8];
    const int*   cols = (const int*)d_in[9];
    const float* vals = (const float*)d_in[10];

    char* ws = (char*)d_ws;
    int*   g_hist  = (int*)(ws);                    // 704*1800*4 = 5,068,800 B
    int*   g_total = (int*)(ws + 5068800);          // 7200 B
    int*   g_base  = (int*)(ws + 5076000);          // 7200 B
    int*   rank    = (int*)(ws + 5083200);          // 720,000 B
    float* dEflat  = (float*)(ws + 5803200);        // 28,800,000 B (16B aligned)

    float* energy = (float*)d_out;                  // [1800]
    float* force  = (float*)d_out + NIMG_;          // [540000]

    const int nOut = NIMG_ + 3 * QTOT;
    zero_kernel<<<(nOut + BLK - 1) / BLK, BLK, 0, stream>>>((float*)d_out, nOut);

    hist_kernel<<<NB, BLK, 0, stream>>>(img, g_hist);
    scan_blocks_kernel<<<NIMG_, BLK, 0, stream>>>(g_hist, g_total);
    scan_buckets_kernel<<<1, BLK, 0, stream>>>(g_total, g_base);
    rank_kernel<<<NB, BLK, 0, stream>>>(img, g_hist, g_base, rank);

    dim3 gm((QE_ + BLK - 1) / BLK, E_);
    mlp_kernel<<<gm, BLK, 0, stream>>>(fps, W1, b1, W2, b2, W3, b3, img, rank,
                                       energy, dEflat);

    force_kernel<<<NNZ_ / BLK, BLK, 0, stream>>>(rows, cols, vals, dEflat, force);
}